// Round 5
// baseline (268.682 us; speedup 1.0000x reference)
//
#include <hip/hip_runtime.h>
#include <math.h>

typedef __bf16 bf16_t;
typedef __bf16 bf16x8 __attribute__((ext_vector_type(8)));
typedef __bf16 bf16x4v __attribute__((ext_vector_type(4)));
typedef float f32x4 __attribute__((ext_vector_type(4)));
typedef float f32x16 __attribute__((ext_vector_type(16)));

#define LOG2E 1.4426950408889634f
#define MBIAS_C (-1e12f * LOG2E)

#if __has_builtin(__builtin_amdgcn_exp2f)
#define EXP2F(x) __builtin_amdgcn_exp2f(x)
#else
#define EXP2F(x) exp2f(x)
#endif

typedef __attribute__((address_space(1))) const unsigned int g_u32;
typedef __attribute__((address_space(3))) unsigned int l_u32;
__device__ __forceinline__ void load_lds_16B(const void* g, void* l){
  __builtin_amdgcn_global_load_lds((g_u32*)g, (l_u32*)l, 16, 0, 0);
}

__device__ __forceinline__ f32x16 zero16(){
  f32x16 z;
  #pragma unroll
  for (int i = 0; i < 16; i++) z[i] = 0.f;
  return z;
}

// ---------------- cast q,k,v fp32 -> bf16 planes ----------------
__global__ __launch_bounds__(256) void cast3_kernel(const float* __restrict__ q,
                                                    const float* __restrict__ k,
                                                    const float* __restrict__ v,
                                                    bf16_t* __restrict__ out){
  int z = blockIdx.y;
  const float* x = (z == 0) ? q : (z == 1) ? k : v;
  int i = blockIdx.x * 256 + threadIdx.x;
  float4 f = reinterpret_cast<const float4*>(x)[i];
  bf16x4v w;
  w[0] = (bf16_t)f.x; w[1] = (bf16_t)f.y; w[2] = (bf16_t)f.z; w[3] = (bf16_t)f.w;
  reinterpret_cast<bf16x4v*>(out + (size_t)z * 4194304)[i] = w;
}

// ---------------- weight transpose+cast ----------------
__global__ __launch_bounds__(256) void wtrans4_kernel(const float* __restrict__ Wq,
                                                      const float* __restrict__ Wk,
                                                      const float* __restrict__ Wv,
                                                      const float* __restrict__ Wo,
                                                      bf16_t* __restrict__ Wcat,
                                                      bf16_t* __restrict__ Wot){
  __shared__ float T[32][33];
  int z = blockIdx.z;
  const float* W = (z == 0) ? Wq : (z == 1) ? Wk : (z == 2) ? Wv : Wo;
  bf16_t* dst = (z < 3) ? (Wcat + (size_t)z * 1024 * 1024) : Wot;
  int x = threadIdx.x, y = threadIdx.y;
  int k0 = blockIdx.y * 32, n0 = blockIdx.x * 32;
  #pragma unroll
  for (int i = 0; i < 4; i++) T[y + 8*i][x] = W[(size_t)(k0 + y + 8*i) * 1024 + n0 + x];
  __syncthreads();
  #pragma unroll
  for (int i = 0; i < 4; i++) dst[(size_t)(n0 + y + 8*i) * 1024 + k0 + x] = (bf16_t)T[x][y + 8*i];
}

// ---------------- shared epilogue for QKV GEMMs ----------------
// seg<2: write plane[row][col] scaled; seg==2: write V transposed to Vt[(b,h,d)][s]
__device__ __forceinline__ void qkv_epilogue(f32x4 (&acc)[4][4], int seg, int n0g, int m0,
                                             int wm, int wn, int l16, int lq,
                                             const float* bias, bf16_t* qp, bf16_t* kp,
                                             bf16_t* Vt){
  if (seg < 2){
    bf16_t* Cp = (seg == 0) ? qp : kp;
    float scale = (seg == 0) ? 0.125f * LOG2E : 1.0f;  // fold softmax scale + log2e into Q
    #pragma unroll
    for (int ti = 0; ti < 4; ti++){
      #pragma unroll
      for (int tj = 0; tj < 4; tj++){
        int col = (n0g + wn + tj*16 + l16) & 1023;
        float bvv = bias[col];
        #pragma unroll
        for (int r = 0; r < 4; r++){
          int row = m0 + wm + ti*16 + lq*4 + r;
          Cp[(size_t)row * 1024 + col] = (bf16_t)((acc[ti][tj][r] + bvv) * scale);
        }
      }
    }
  } else {
    #pragma unroll
    for (int ti = 0; ti < 4; ti++){
      #pragma unroll
      for (int tj = 0; tj < 4; tj++){
        int dg = (n0g - 2048) + wn + tj*16 + l16;  // 0..1023
        int h = dg >> 6, dl = dg & 63;
        float bvv = bias[dg];
        #pragma unroll
        for (int r = 0; r < 4; r++){
          int row = m0 + wm + ti*16 + lq*4 + r;
          int b = row >> 11, s = row & 2047;
          Vt[(size_t)((b*16 + h)*64 + dl) * 2048 + s] = (bf16_t)(acc[ti][tj][r] + bvv);
        }
      }
    }
  }
}

// ---------------- fused QKV GEMM, all-bf16 (path A) ----------------
__global__ __launch_bounds__(256) void gemm_qkv_bf(const bf16_t* __restrict__ qkvin,
                                                   const bf16_t* __restrict__ Wcat,
                                                   const float* __restrict__ bq,
                                                   const float* __restrict__ bk,
                                                   const float* __restrict__ bv,
                                                   bf16_t* __restrict__ qp,
                                                   bf16_t* __restrict__ kp,
                                                   bf16_t* __restrict__ Vt){
  const int K = 1024;
  __shared__ __align__(16) bf16_t As[128*32];
  __shared__ __align__(16) bf16_t Bs[128*32];
  int tid = threadIdx.x, wave = tid >> 6, lane = tid & 63;
  int l16 = lane & 15, lq = lane >> 4;
  int n0g = blockIdx.x * 128;
  int seg = n0g >> 10;
  const bf16_t* A   = qkvin + (size_t)seg * 4194304;
  const float* bias = (seg == 0) ? bq : (seg == 1) ? bk : bv;
  int m0 = blockIdx.y * 128;
  int wm = (wave >> 1) * 64, wn = (wave & 1) * 64;
  int cposR = lq ^ ((l16 >> 2) & 3);
  f32x4 acc[4][4] = {};
  for (int kt = 0; kt < K; kt += 32){
    __syncthreads();
    #pragma unroll
    for (int i = 0; i < 2; i++){
      int u = tid + 256*i;
      int r = u >> 2, cpos = u & 3, cg = cpos ^ ((r >> 2) & 3);
      int ldsoff = (wave*64 + 256*i) * 16;
      load_lds_16B(&A[(size_t)(m0 + r) * K + kt + cg*8], (char*)As + ldsoff);
      load_lds_16B(&Wcat[(size_t)(n0g + r) * K + kt + cg*8], (char*)Bs + ldsoff);
    }
    __syncthreads();
    bf16x8 af[4], bfr[4];
    #pragma unroll
    for (int t = 0; t < 4; t++) af[t]  = *reinterpret_cast<bf16x8*>(&As[(wm + t*16 + l16)*32 + cposR*8]);
    #pragma unroll
    for (int t = 0; t < 4; t++) bfr[t] = *reinterpret_cast<bf16x8*>(&Bs[(wn + t*16 + l16)*32 + cposR*8]);
    #pragma unroll
    for (int ti = 0; ti < 4; ti++)
      #pragma unroll
      for (int tj = 0; tj < 4; tj++)
        acc[ti][tj] = __builtin_amdgcn_mfma_f32_16x16x32_bf16(af[ti], bfr[tj], acc[ti][tj], 0, 0, 0);
  }
  qkv_epilogue(acc, seg, n0g, m0, wm, wn, l16, lq, bias, qp, kp, Vt);
}

// ---------------- fused QKV GEMM, fp32-A fused-cvt (path B fallback) ----------------
__global__ __launch_bounds__(256) void gemm_qkv_f32(const float* __restrict__ qi,
                                                    const float* __restrict__ ki,
                                                    const float* __restrict__ vi,
                                                    const bf16_t* __restrict__ Wcat,
                                                    const float* __restrict__ bq,
                                                    const float* __restrict__ bk,
                                                    const float* __restrict__ bv,
                                                    bf16_t* __restrict__ qp,
                                                    bf16_t* __restrict__ kp,
                                                    bf16_t* __restrict__ Vt){
  const int K = 1024;
  __shared__ __align__(16) float  Asf[128*32];
  __shared__ __align__(16) bf16_t Bs[128*32];
  int tid = threadIdx.x, wave = tid >> 6, lane = tid & 63;
  int l16 = lane & 15, lq = lane >> 4;
  int n0g = blockIdx.x * 128;
  int seg = n0g >> 10;
  const float* A    = (seg == 0) ? qi : (seg == 1) ? ki : vi;
  const float* bias = (seg == 0) ? bq : (seg == 1) ? bk : bv;
  int m0 = blockIdx.y * 128;
  int wm = (wave >> 1) * 64, wn = (wave & 1) * 64;
  int cposR = lq ^ ((l16 >> 2) & 3);
  int ca0 = (2*lq)     ^ (l16 & 7);
  int ca1 = (2*lq + 1) ^ (l16 & 7);
  f32x4 acc[4][4] = {};
  for (int kt = 0; kt < K; kt += 32){
    __syncthreads();
    #pragma unroll
    for (int i = 0; i < 4; i++){
      int u = tid + 256*i;
      int r = u >> 3, cpos = u & 7, cg = cpos ^ (r & 7);
      load_lds_16B(&A[(size_t)(m0 + r) * K + kt + cg*4], (char*)Asf + (wave*64 + 256*i)*16);
    }
    #pragma unroll
    for (int i = 0; i < 2; i++){
      int u = tid + 256*i;
      int r = u >> 2, cpos = u & 3, cg = cpos ^ ((r >> 2) & 3);
      load_lds_16B(&Wcat[(size_t)(n0g + r) * K + kt + cg*8], (char*)Bs + (wave*64 + 256*i)*16);
    }
    __syncthreads();
    bf16x8 af[4], bfr[4];
    #pragma unroll
    for (int t = 0; t < 4; t++){
      int row = wm + t*16 + l16;
      f32x4 x0 = *reinterpret_cast<f32x4*>(&Asf[row*32 + ca0*4]);
      f32x4 x1 = *reinterpret_cast<f32x4*>(&Asf[row*32 + ca1*4]);
      bf16x8 a;
      a[0] = (bf16_t)x0[0]; a[1] = (bf16_t)x0[1]; a[2] = (bf16_t)x0[2]; a[3] = (bf16_t)x0[3];
      a[4] = (bf16_t)x1[0]; a[5] = (bf16_t)x1[1]; a[6] = (bf16_t)x1[2]; a[7] = (bf16_t)x1[3];
      af[t] = a;
    }
    #pragma unroll
    for (int t = 0; t < 4; t++) bfr[t] = *reinterpret_cast<bf16x8*>(&Bs[(wn + t*16 + l16)*32 + cposR*8]);
    #pragma unroll
    for (int ti = 0; ti < 4; ti++)
      #pragma unroll
      for (int tj = 0; tj < 4; tj++)
        acc[ti][tj] = __builtin_amdgcn_mfma_f32_16x16x32_bf16(af[ti], bfr[tj], acc[ti][tj], 0, 0, 0);
  }
  qkv_epilogue(acc, seg, n0g, m0, wm, wn, l16, lq, bias, qp, kp, Vt);
}

// ---------------- output GEMM: d_out = ctx @ Wot^T + bo, fp32 out ----------------
__global__ __launch_bounds__(256) void gemm_out(const bf16_t* __restrict__ A,
                                                const bf16_t* __restrict__ Bt,
                                                const float* __restrict__ bias,
                                                float* __restrict__ C){
  const int K = 1024, N = 1024;
  __shared__ __align__(16) bf16_t As[128*64];
  __shared__ __align__(16) bf16_t Bs[64*64];
  int tid = threadIdx.x, wave = tid >> 6, lane = tid & 63;
  int l16 = lane & 15, lq = lane >> 4;
  int m0 = blockIdx.y * 128, n0 = blockIdx.x * 64;
  int wm = wave * 32;
  f32x4 acc[2][4] = {};
  for (int kt = 0; kt < K; kt += 64){
    __syncthreads();
    #pragma unroll
    for (int i = 0; i < 4; i++){
      int u = tid + 256*i;
      int r = u >> 3, cpos = u & 7, cg = cpos ^ (r & 7);
      load_lds_16B(&A[(size_t)(m0 + r) * K + kt + cg*8], (char*)As + (wave*64 + 256*i)*16);
    }
    #pragma unroll
    for (int i = 0; i < 2; i++){
      int u = tid + 256*i;
      int r = u >> 3, cpos = u & 7, cg = cpos ^ (r & 7);
      load_lds_16B(&Bt[(size_t)(n0 + r) * K + kt + cg*8], (char*)Bs + (wave*64 + 256*i)*16);
    }
    __syncthreads();
    #pragma unroll
    for (int kk = 0; kk < 2; kk++){
      bf16x8 af[2], bfr[4];
      #pragma unroll
      for (int t = 0; t < 2; t++){
        int row = wm + t*16 + l16, cpos = (kk*4 + lq) ^ (l16 & 7);
        af[t] = *reinterpret_cast<bf16x8*>(&As[row*64 + cpos*8]);
      }
      #pragma unroll
      for (int t = 0; t < 4; t++){
        int row = t*16 + l16, cpos = (kk*4 + lq) ^ (l16 & 7);
        bfr[t] = *reinterpret_cast<bf16x8*>(&Bs[row*64 + cpos*8]);
      }
      #pragma unroll
      for (int ti = 0; ti < 2; ti++)
        #pragma unroll
        for (int tj = 0; tj < 4; tj++)
          acc[ti][tj] = __builtin_amdgcn_mfma_f32_16x16x32_bf16(af[ti], bfr[tj], acc[ti][tj], 0, 0, 0);
    }
  }
  #pragma unroll
  for (int ti = 0; ti < 2; ti++){
    #pragma unroll
    for (int tj = 0; tj < 4; tj++){
      int col = n0 + tj*16 + l16;
      float bvv = bias[col];
      #pragma unroll
      for (int r = 0; r < 4; r++){
        int row = m0 + wm + ti*16 + lq*4 + r;
        C[(size_t)row * N + col] = acc[ti][tj][r] + bvv;
      }
    }
  }
}

// ---------------- flash attention, 32x32x16 MFMA ----------------
// Block: 64 q-rows; per k-tile 64 keys. Wave (qhalf, khalf) computes the 32x32 score
// tile Sc^T[kcol][qrow]; each lane owns one q-col -> softmax is local+1 shfl.
// P round-trips LDS (stride-40 rows); PV accumulates per-k-half partial O, combined
// through LDS in the epilogue. l via local adds (no ones-MFMA, no running max).
__global__ __launch_bounds__(256) void attn_kernel(const bf16_t* __restrict__ qp,
                                                   const bf16_t* __restrict__ kp,
                                                   const bf16_t* __restrict__ vt,
                                                   const float* __restrict__ mask,
                                                   bf16_t* __restrict__ ctx){
  const int S = 2048, D = 1024, HD = 64;
  __shared__ __align__(16) char smem[26624];
  bf16_t* Qs   = (bf16_t*)smem;              // [64][64] 8 KB (dead after preload)
  bf16_t* Ps   = (bf16_t*)smem;              // 4 waves x 32 rows x 40 elems = 10,240 B
  bf16_t* Ks   = (bf16_t*)(smem + 10240);    // [64][64] 8 KB
  bf16_t* Vts  = (bf16_t*)(smem + 18432);    // [64][64] 8 KB ([d][s])
  float* Opart = (float*)smem;               // epilogue: [2 qhalf][32 regs][64 lanes]
  float* Lsum  = (float*)(smem + 16384);     // [2][32]
  float* Lcomb = (float*)(smem + 16640);     // [2][32]
  int tid = threadIdx.x, wave = tid >> 6, lane = tid & 63;
  int l32 = lane & 31, H = lane >> 5;
  int qhalf = wave & 1, khalf = wave >> 1;
  int qt = blockIdx.x, h = blockIdx.y, b = blockIdx.z;
  const bf16_t* Qg = qp + (size_t)b*S*D + h*HD;
  const bf16_t* Kg = kp + (size_t)b*S*D + h*HD;
  const bf16_t* Vg = vt + (size_t)(b*16 + h)*HD*S;

  // stage Q (64x64, chunk-swizzled)
  #pragma unroll
  for (int i = 0; i < 2; i++){
    int u = tid + 256*i;
    int r = u >> 3, c = u & 7, cg = c ^ (r & 7);
    load_lds_16B(&Qg[(size_t)(qt*64 + r) * D + cg*8], smem + (wave*64 + 256*i)*16);
  }
  __syncthreads();
  // Q fragments (B-operand): lane n=qrow=qhalf*32+l32, k=d=16s+8H+j
  int qrow = qhalf*32 + l32;
  bf16x8 qf[4];
  #pragma unroll
  for (int s = 0; s < 4; s++){
    int c = 2*s + H;
    qf[s] = *reinterpret_cast<bf16x8*>(&Qs[qrow*64 + (c ^ (qrow & 7))*8]);
  }
  f32x16 o0 = zero16(), o1 = zero16();
  float lacc = 0.f;
  int krow = khalf*32 + l32;
  bf16_t* Pw = Ps + wave*32*40;

  for (int kt = 0; kt < S; kt += 64){
    __syncthreads();
    #pragma unroll
    for (int i = 0; i < 2; i++){
      int u = tid + 256*i;
      int r = u >> 3, c = u & 7, cg = c ^ (r & 7);
      load_lds_16B(&Kg[(size_t)(kt + r) * D + cg*8], (char*)Ks + (wave*64 + 256*i)*16);
    }
    #pragma unroll
    for (int i = 0; i < 2; i++){
      int u = tid + 256*i;
      int r = u >> 3, c = u & 7, cg = c ^ (r & 7);
      load_lds_16B(&Vg[(size_t)r * S + kt + cg*8], (char*)Vts + (wave*64 + 256*i)*16);
    }
    __syncthreads();

    // QK: Sc^T[m=kcol 32][n=qrow 32], K-dim d=64 -> 4 MFMA
    f32x16 sc;
    #pragma unroll
    for (int s = 0; s < 4; s++){
      int c = 2*s + H;
      bf16x8 kf = *reinterpret_cast<bf16x8*>(&Ks[krow*64 + (c ^ (krow & 7))*8]);
      if (s == 0) sc = __builtin_amdgcn_mfma_f32_32x32x16_bf16(kf, qf[0], zero16(), 0, 0, 0);
      else        sc = __builtin_amdgcn_mfma_f32_32x32x16_bf16(kf, qf[s], sc, 0, 0, 0);
    }
    // softmax (no max-sub; scores already in log2 domain via Q scale)
    // lane owns q-col = l32; rows k = (reg&3) + 8*(reg>>2) + 4*H
    float lt = 0.f;
    #pragma unroll
    for (int g = 0; g < 4; g++){
      int kcol = kt + khalf*32 + 8*g + 4*H;
      float4 mv = *reinterpret_cast<const float4*>(&mask[(size_t)b*S + kcol]);
      float p0 = EXP2F(fmaf(mv.x, MBIAS_C, sc[4*g+0]));
      float p1 = EXP2F(fmaf(mv.y, MBIAS_C, sc[4*g+1]));
      float p2 = EXP2F(fmaf(mv.z, MBIAS_C, sc[4*g+2]));
      float p3 = EXP2F(fmaf(mv.w, MBIAS_C, sc[4*g+3]));
      lt += (p0 + p1) + (p2 + p3);
      bf16x4v w;
      w[0] = (bf16_t)p0; w[1] = (bf16_t)p1; w[2] = (bf16_t)p2; w[3] = (bf16_t)p3;
      *reinterpret_cast<bf16x4v*>(&Pw[l32*40 + 8*g + 4*H]) = w;
    }
    lt += __shfl_xor(lt, 32);
    lacc += lt;
    // PV: O_partial[q 32][d 64] += P[q 32][k 32] * V[k 32][d 64]  (2 k-steps)
    #pragma unroll
    for (int ks = 0; ks < 2; ks++){
      bf16x8 pf = *reinterpret_cast<bf16x8*>(&Pw[l32*40 + ks*16 + 8*H]);
      int c0 = 4*khalf + 2*ks + H;
      bf16x8 vf0 = *reinterpret_cast<bf16x8*>(&Vts[l32*64 + (c0 ^ (l32 & 7))*8]);
      bf16x8 vf1 = *reinterpret_cast<bf16x8*>(&Vts[(32 + l32)*64 + (c0 ^ (l32 & 7))*8]);
      o0 = __builtin_amdgcn_mfma_f32_32x32x16_bf16(pf, vf0, o0, 0, 0, 0);
      o1 = __builtin_amdgcn_mfma_f32_32x32x16_bf16(pf, vf1, o1, 0, 0, 0);
    }
  }
  // epilogue: combine k-halves through LDS, normalize, store
  __syncthreads();
  if (khalf == 1){
    #pragma unroll
    for (int reg = 0; reg < 16; reg++){
      Opart[qhalf*2048 + reg*64 + lane]        = o0[reg];
      Opart[qhalf*2048 + 1024 + reg*64 + lane] = o1[reg];
    }
    Lsum[qhalf*32 + l32] = lacc;  // both H lanes write the same value (benign)
  }
  __syncthreads();
  if (khalf == 0){
    #pragma unroll
    for (int reg = 0; reg < 16; reg++){
      o0[reg] += Opart[qhalf*2048 + reg*64 + lane];
      o1[reg] += Opart[qhalf*2048 + 1024 + reg*64 + lane];
    }
    lacc += Lsum[qhalf*32 + l32];
    Lcomb[qhalf*32 + l32] = lacc;  // same-wave write->read, no barrier needed
    #pragma unroll
    for (int g = 0; g < 4; g++){
      f32x4 lv = *reinterpret_cast<f32x4*>(&Lcomb[qhalf*32 + 8*g + 4*H]);
      #pragma unroll
      for (int j = 0; j < 4; j++){
        float inv = 1.f / lv[j];
        int grow = qt*64 + qhalf*32 + 8*g + 4*H + j;
        size_t base = (size_t)(b*S + grow) * D + h*HD;
        ctx[base + l32]      = (bf16_t)(o0[4*g + j] * inv);
        ctx[base + 32 + l32] = (bf16_t)(o1[4*g + j] * inv);
      }
    }
  }
}

extern "C" void kernel_launch(void* const* d_in, const int* in_sizes, int n_in,
                              void* d_out, int out_size, void* d_ws, size_t ws_size,
                              hipStream_t stream){
  const float* q    = (const float*)d_in[0];
  const float* k    = (const float*)d_in[1];
  const float* v    = (const float*)d_in[2];
  const float* mask = (const float*)d_in[3];
  const float* Wq   = (const float*)d_in[4];
  const float* bq   = (const float*)d_in[5];
  const float* Wk   = (const float*)d_in[6];
  const float* bk   = (const float*)d_in[7];
  const float* Wv   = (const float*)d_in[8];
  const float* bv   = (const float*)d_in[9];
  const float* Wo   = (const float*)d_in[10];
  const float* bo   = (const float*)d_in[11];

  char* ws = (char*)d_ws;
  bf16_t* qp    = (bf16_t*)(ws);               // [0, 8 MiB)   q plane
  bf16_t* kp    = (bf16_t*)(ws + 8388608);     // [8, 16)      k plane
  bf16_t* Vt    = (bf16_t*)(ws + 16777216);    // [16, 24)     V transposed [(b,h,d)][s]
  bf16_t* Wcat  = (bf16_t*)(ws + 25165824);    // [24, 30)
  bf16_t* Wot   = (bf16_t*)(ws + 31457280);    // [30, 32)
  bf16_t* ctx   = (bf16_t*)(ws + 33554432);    // [32, 40)  (reuses qkvin region after it dies)
  bf16_t* qkvin = (bf16_t*)(ws + 33554432);    // [32, 56)  path A only

  wtrans4_kernel<<<dim3(32,32,4), dim3(32,8), 0, stream>>>(Wq, Wk, Wv, Wo, Wcat, Wot);
  if (ws_size >= 58720256){
    cast3_kernel<<<dim3(4096,3), 256, 0, stream>>>(q, k, v, qkvin);
    gemm_qkv_bf<<<dim3(24,32), 256, 0, stream>>>(qkvin, Wcat, bq, bk, bv, qp, kp, Vt);
  } else {
    gemm_qkv_f32<<<dim3(24,32), 256, 0, stream>>>(q, k, v, Wcat, bq, bk, bv, qp, kp, Vt);
  }
  attn_kernel<<<dim3(32,16,2), 256, 0, stream>>>(qp, kp, Vt, mask, ctx);
  gemm_out<<<dim3(16,32), 256, 0, stream>>>(ctx, Wot, bo, (float*)d_out);
}

// Round 6
// 263.805 us; speedup vs baseline: 1.0185x; 1.0185x over previous
//
#include <hip/hip_runtime.h>
#include <math.h>

typedef __bf16 bf16_t;
typedef __bf16 bf16x8 __attribute__((ext_vector_type(8)));
typedef __bf16 bf16x4v __attribute__((ext_vector_type(4)));
typedef float f32x4 __attribute__((ext_vector_type(4)));
typedef float f32x16 __attribute__((ext_vector_type(16)));

#define LOG2E 1.4426950408889634f
#define MBIAS_C (-1e12f * LOG2E)

#if __has_builtin(__builtin_amdgcn_exp2f)
#define EXP2F(x) __builtin_amdgcn_exp2f(x)
#else
#define EXP2F(x) exp2f(x)
#endif

typedef __attribute__((address_space(1))) const unsigned int g_u32;
typedef __attribute__((address_space(3))) unsigned int l_u32;
__device__ __forceinline__ void load_lds_16B(const void* g, void* l){
  __builtin_amdgcn_global_load_lds((g_u32*)g, (l_u32*)l, 16, 0, 0);
}

__device__ __forceinline__ f32x16 zero16(){
  f32x16 z;
  #pragma unroll
  for (int i = 0; i < 16; i++) z[i] = 0.f;
  return z;
}

typedef union { bf16x4v b4; uint2 u2; } pk8;
typedef union { uint2 h[2]; bf16x8 b8; } pk16;

// ---------------- cast q,k,v fp32 -> bf16 planes ----------------
__global__ __launch_bounds__(256) void cast3_kernel(const float* __restrict__ q,
                                                    const float* __restrict__ k,
                                                    const float* __restrict__ v,
                                                    bf16_t* __restrict__ out){
  int z = blockIdx.y;
  const float* x = (z == 0) ? q : (z == 1) ? k : v;
  int i = blockIdx.x * 256 + threadIdx.x;
  float4 f = reinterpret_cast<const float4*>(x)[i];
  bf16x4v w;
  w[0] = (bf16_t)f.x; w[1] = (bf16_t)f.y; w[2] = (bf16_t)f.z; w[3] = (bf16_t)f.w;
  reinterpret_cast<bf16x4v*>(out + (size_t)z * 4194304)[i] = w;
}

// ---------------- weight transpose+cast ----------------
__global__ __launch_bounds__(256) void wtrans4_kernel(const float* __restrict__ Wq,
                                                      const float* __restrict__ Wk,
                                                      const float* __restrict__ Wv,
                                                      const float* __restrict__ Wo,
                                                      bf16_t* __restrict__ Wcat,
                                                      bf16_t* __restrict__ Wot){
  __shared__ float T[32][33];
  int z = blockIdx.z;
  const float* W = (z == 0) ? Wq : (z == 1) ? Wk : (z == 2) ? Wv : Wo;
  bf16_t* dst = (z < 3) ? (Wcat + (size_t)z * 1024 * 1024) : Wot;
  int x = threadIdx.x, y = threadIdx.y;
  int k0 = blockIdx.y * 32, n0 = blockIdx.x * 32;
  #pragma unroll
  for (int i = 0; i < 4; i++) T[y + 8*i][x] = W[(size_t)(k0 + y + 8*i) * 1024 + n0 + x];
  __syncthreads();
  #pragma unroll
  for (int i = 0; i < 4; i++) dst[(size_t)(n0 + y + 8*i) * 1024 + k0 + x] = (bf16_t)T[x][y + 8*i];
}

// ---------------- shared epilogue for QKV GEMMs: write q/k/v planes ----------------
__device__ __forceinline__ void qkv_epilogue(f32x4 (&acc)[4][4], int seg, int n0g, int m0,
                                             int wm, int wn, int l16, int lq,
                                             const float* bias, bf16_t* qp, bf16_t* kp,
                                             bf16_t* vh){
  bf16_t* Cp = (seg == 0) ? qp : (seg == 1) ? kp : vh;
  float scale = (seg == 0) ? 0.125f * LOG2E : 1.0f;  // fold softmax scale + log2e into Q
  #pragma unroll
  for (int ti = 0; ti < 4; ti++){
    #pragma unroll
    for (int tj = 0; tj < 4; tj++){
      int col = (n0g + wn + tj*16 + l16) & 1023;
      float bvv = bias[col];
      #pragma unroll
      for (int r = 0; r < 4; r++){
        int row = m0 + wm + ti*16 + lq*4 + r;
        Cp[(size_t)row * 1024 + col] = (bf16_t)((acc[ti][tj][r] + bvv) * scale);
      }
    }
  }
}

// ---------------- fused QKV GEMM, all-bf16 (path A) ----------------
__global__ __launch_bounds__(256) void gemm_qkv_bf(const bf16_t* __restrict__ qkvin,
                                                   const bf16_t* __restrict__ Wcat,
                                                   const float* __restrict__ bq,
                                                   const float* __restrict__ bk,
                                                   const float* __restrict__ bv,
                                                   bf16_t* __restrict__ qp,
                                                   bf16_t* __restrict__ kp,
                                                   bf16_t* __restrict__ vh){
  const int K = 1024;
  __shared__ __align__(16) bf16_t As[128*32];
  __shared__ __align__(16) bf16_t Bs[128*32];
  int tid = threadIdx.x, wave = tid >> 6, lane = tid & 63;
  int l16 = lane & 15, lq = lane >> 4;
  int n0g = blockIdx.x * 128;
  int seg = n0g >> 10;
  const bf16_t* A   = qkvin + (size_t)seg * 4194304;
  const float* bias = (seg == 0) ? bq : (seg == 1) ? bk : bv;
  int m0 = blockIdx.y * 128;
  int wm = (wave >> 1) * 64, wn = (wave & 1) * 64;
  int cposR = lq ^ ((l16 >> 2) & 3);
  f32x4 acc[4][4] = {};
  for (int kt = 0; kt < K; kt += 32){
    __syncthreads();
    #pragma unroll
    for (int i = 0; i < 2; i++){
      int u = tid + 256*i;
      int r = u >> 2, cpos = u & 3, cg = cpos ^ ((r >> 2) & 3);
      int ldsoff = (wave*64 + 256*i) * 16;
      load_lds_16B(&A[(size_t)(m0 + r) * K + kt + cg*8], (char*)As + ldsoff);
      load_lds_16B(&Wcat[(size_t)(n0g + r) * K + kt + cg*8], (char*)Bs + ldsoff);
    }
    __syncthreads();
    bf16x8 af[4], bfr[4];
    #pragma unroll
    for (int t = 0; t < 4; t++) af[t]  = *reinterpret_cast<bf16x8*>(&As[(wm + t*16 + l16)*32 + cposR*8]);
    #pragma unroll
    for (int t = 0; t < 4; t++) bfr[t] = *reinterpret_cast<bf16x8*>(&Bs[(wn + t*16 + l16)*32 + cposR*8]);
    #pragma unroll
    for (int ti = 0; ti < 4; ti++)
      #pragma unroll
      for (int tj = 0; tj < 4; tj++)
        acc[ti][tj] = __builtin_amdgcn_mfma_f32_16x16x32_bf16(af[ti], bfr[tj], acc[ti][tj], 0, 0, 0);
  }
  qkv_epilogue(acc, seg, n0g, m0, wm, wn, l16, lq, bias, qp, kp, vh);
}

// ---------------- fused QKV GEMM, fp32-A fused-cvt (path B fallback) ----------------
__global__ __launch_bounds__(256) void gemm_qkv_f32(const float* __restrict__ qi,
                                                    const float* __restrict__ ki,
                                                    const float* __restrict__ vi,
                                                    const bf16_t* __restrict__ Wcat,
                                                    const float* __restrict__ bq,
                                                    const float* __restrict__ bk,
                                                    const float* __restrict__ bv,
                                                    bf16_t* __restrict__ qp,
                                                    bf16_t* __restrict__ kp,
                                                    bf16_t* __restrict__ vh){
  const int K = 1024;
  __shared__ __align__(16) float  Asf[128*32];
  __shared__ __align__(16) bf16_t Bs[128*32];
  int tid = threadIdx.x, wave = tid >> 6, lane = tid & 63;
  int l16 = lane & 15, lq = lane >> 4;
  int n0g = blockIdx.x * 128;
  int seg = n0g >> 10;
  const float* A    = (seg == 0) ? qi : (seg == 1) ? ki : vi;
  const float* bias = (seg == 0) ? bq : (seg == 1) ? bk : bv;
  int m0 = blockIdx.y * 128;
  int wm = (wave >> 1) * 64, wn = (wave & 1) * 64;
  int cposR = lq ^ ((l16 >> 2) & 3);
  int ca0 = (2*lq)     ^ (l16 & 7);
  int ca1 = (2*lq + 1) ^ (l16 & 7);
  f32x4 acc[4][4] = {};
  for (int kt = 0; kt < K; kt += 32){
    __syncthreads();
    #pragma unroll
    for (int i = 0; i < 4; i++){
      int u = tid + 256*i;
      int r = u >> 3, cpos = u & 7, cg = cpos ^ (r & 7);
      load_lds_16B(&A[(size_t)(m0 + r) * K + kt + cg*4], (char*)Asf + (wave*64 + 256*i)*16);
    }
    #pragma unroll
    for (int i = 0; i < 2; i++){
      int u = tid + 256*i;
      int r = u >> 2, cpos = u & 3, cg = cpos ^ ((r >> 2) & 3);
      load_lds_16B(&Wcat[(size_t)(n0g + r) * K + kt + cg*8], (char*)Bs + (wave*64 + 256*i)*16);
    }
    __syncthreads();
    bf16x8 af[4], bfr[4];
    #pragma unroll
    for (int t = 0; t < 4; t++){
      int row = wm + t*16 + l16;
      f32x4 x0 = *reinterpret_cast<f32x4*>(&Asf[row*32 + ca0*4]);
      f32x4 x1 = *reinterpret_cast<f32x4*>(&Asf[row*32 + ca1*4]);
      bf16x8 a;
      a[0] = (bf16_t)x0[0]; a[1] = (bf16_t)x0[1]; a[2] = (bf16_t)x0[2]; a[3] = (bf16_t)x0[3];
      a[4] = (bf16_t)x1[0]; a[5] = (bf16_t)x1[1]; a[6] = (bf16_t)x1[2]; a[7] = (bf16_t)x1[3];
      af[t] = a;
    }
    #pragma unroll
    for (int t = 0; t < 4; t++) bfr[t] = *reinterpret_cast<bf16x8*>(&Bs[(wn + t*16 + l16)*32 + cposR*8]);
    #pragma unroll
    for (int ti = 0; ti < 4; ti++)
      #pragma unroll
      for (int tj = 0; tj < 4; tj++)
        acc[ti][tj] = __builtin_amdgcn_mfma_f32_16x16x32_bf16(af[ti], bfr[tj], acc[ti][tj], 0, 0, 0);
  }
  qkv_epilogue(acc, seg, n0g, m0, wm, wn, l16, lq, bias, qp, kp, vh);
}

// ---------------- output GEMM: d_out = ctx @ Wot^T + bo, fp32 out ----------------
__global__ __launch_bounds__(256) void gemm_out(const bf16_t* __restrict__ A,
                                                const bf16_t* __restrict__ Bt,
                                                const float* __restrict__ bias,
                                                float* __restrict__ C){
  const int K = 1024, N = 1024;
  __shared__ __align__(16) bf16_t As[128*64];
  __shared__ __align__(16) bf16_t Bs[64*64];
  int tid = threadIdx.x, wave = tid >> 6, lane = tid & 63;
  int l16 = lane & 15, lq = lane >> 4;
  int m0 = blockIdx.y * 128, n0 = blockIdx.x * 64;
  int wm = wave * 32;
  f32x4 acc[2][4] = {};
  for (int kt = 0; kt < K; kt += 64){
    __syncthreads();
    #pragma unroll
    for (int i = 0; i < 4; i++){
      int u = tid + 256*i;
      int r = u >> 3, cpos = u & 7, cg = cpos ^ (r & 7);
      load_lds_16B(&A[(size_t)(m0 + r) * K + kt + cg*8], (char*)As + (wave*64 + 256*i)*16);
    }
    #pragma unroll
    for (int i = 0; i < 2; i++){
      int u = tid + 256*i;
      int r = u >> 3, cpos = u & 7, cg = cpos ^ (r & 7);
      load_lds_16B(&Bt[(size_t)(n0 + r) * K + kt + cg*8], (char*)Bs + (wave*64 + 256*i)*16);
    }
    __syncthreads();
    #pragma unroll
    for (int kk = 0; kk < 2; kk++){
      bf16x8 af[2], bfr[4];
      #pragma unroll
      for (int t = 0; t < 2; t++){
        int row = wm + t*16 + l16, cpos = (kk*4 + lq) ^ (l16 & 7);
        af[t] = *reinterpret_cast<bf16x8*>(&As[row*64 + cpos*8]);
      }
      #pragma unroll
      for (int t = 0; t < 4; t++){
        int row = t*16 + l16, cpos = (kk*4 + lq) ^ (l16 & 7);
        bfr[t] = *reinterpret_cast<bf16x8*>(&Bs[row*64 + cpos*8]);
      }
      #pragma unroll
      for (int ti = 0; ti < 2; ti++)
        #pragma unroll
        for (int tj = 0; tj < 4; tj++)
          acc[ti][tj] = __builtin_amdgcn_mfma_f32_16x16x32_bf16(af[ti], bfr[tj], acc[ti][tj], 0, 0, 0);
    }
  }
  #pragma unroll
  for (int ti = 0; ti < 2; ti++){
    #pragma unroll
    for (int tj = 0; tj < 4; tj++){
      int col = n0 + tj*16 + l16;
      float bvv = bias[col];
      #pragma unroll
      for (int r = 0; r < 4; r++){
        int row = m0 + wm + ti*16 + lq*4 + r;
        C[(size_t)row * N + col] = acc[ti][tj][r] + bvv;
      }
    }
  }
}

// ---------------- per-head V transpose: vh[b*2048+s][h*64+d] -> Vt[(b*16+h)*64+d][s] ----------------
__global__ __launch_bounds__(256) void vtrans_kernel(const bf16_t* __restrict__ vh,
                                                     bf16_t* __restrict__ Vt){
  __shared__ bf16_t T[64][72];
  int tid = threadIdx.x;
  int s0 = blockIdx.x * 64, h = blockIdx.y, b = blockIdx.z;
  #pragma unroll
  for (int i = 0; i < 2; i++){
    int u = tid + 256*i;
    int r = u >> 3, c = (u & 7) * 8;
    *reinterpret_cast<uint4*>(&T[r][c]) =
      *reinterpret_cast<const uint4*>(&vh[(size_t)(b*2048 + s0 + r) * 1024 + h*64 + c]);
  }
  __syncthreads();
  #pragma unroll
  for (int i = 0; i < 2; i++){
    int u = tid + 256*i;
    int d = u >> 3, cs = (u & 7) * 8;
    bf16_t t8[8];
    #pragma unroll
    for (int j = 0; j < 8; j++) t8[j] = T[cs + j][d];
    *reinterpret_cast<uint4*>(&Vt[(size_t)((b*16 + h)*64 + d) * 2048 + s0 + cs]) =
      *reinterpret_cast<uint4*>(t8);
  }
}

// ---------------- flash attention v3: 32x32x16 MFMA, register P-transpose ----------------
// Block: 128 q-rows, 4 waves (each 32 q). K-tile 64. Per tile:
//   Sc^T[k][q] = mfma(K_frag, Q_frag) -> lane owns q-col l32, 32 kcols.
//   exp in regs; P transposed C-layout->A-layout with 2 shfl_xor(32) per k16-window
//   (NO LDS round-trip, no Ps buffer). PV: O[q][d] += P@V.
// LDS: Ks 8K + Vts 8K + Lbuf 0.5K = 16.9 KB. Q frags loaded from global (one-time).
__global__ __launch_bounds__(256) void attn_kernel(const bf16_t* __restrict__ qp,
                                                   const bf16_t* __restrict__ kp,
                                                   const bf16_t* __restrict__ vt,
                                                   const float* __restrict__ mask,
                                                   bf16_t* __restrict__ ctx){
  const int S = 2048, D = 1024, HD = 64;
  __shared__ __align__(16) char smem[16896];
  bf16_t* Ks  = (bf16_t*)smem;             // [64][64] 8 KB
  bf16_t* Vts = (bf16_t*)(smem + 8192);    // [64][64] 8 KB  ([d][s])
  float* Lbuf = (float*)(smem + 16384);    // [4][32]
  int tid = threadIdx.x, wave = tid >> 6, lane = tid & 63;
  int l32 = lane & 31, H = lane >> 5;
  int qt = blockIdx.x, h = blockIdx.y, b = blockIdx.z;
  const bf16_t* Qg = qp + (size_t)b*S*D + h*HD;
  const bf16_t* Kg = kp + (size_t)b*S*D + h*HD;
  const bf16_t* Vg = vt + (size_t)(b*16 + h)*HD*S;

  // Q fragments straight from global: B-operand, lane n=qrow, k=d=16s+8H+j
  int qrow = qt*128 + wave*32 + l32;
  bf16x8 qf[4];
  #pragma unroll
  for (int s = 0; s < 4; s++)
    qf[s] = *reinterpret_cast<const bf16x8*>(&Qg[(size_t)qrow * D + s*16 + 8*H]);

  f32x16 o0 = zero16(), o1 = zero16();
  float lacc = 0.f;

  for (int kt = 0; kt < S; kt += 64){
    __syncthreads();
    #pragma unroll
    for (int i = 0; i < 2; i++){
      int u = tid + 256*i;
      int r = u >> 3, c = u & 7, cg = c ^ (r & 7);
      load_lds_16B(&Kg[(size_t)(kt + r) * D + cg*8], (char*)Ks + (wave*64 + 256*i)*16);
    }
    #pragma unroll
    for (int i = 0; i < 2; i++){
      int u = tid + 256*i;
      int r = u >> 3, c = u & 7, cg = c ^ (r & 7);
      load_lds_16B(&Vg[(size_t)r * S + kt + cg*8], (char*)Vts + (wave*64 + 256*i)*16);
    }
    __syncthreads();

    // QK: two 32x32 Sc^T tiles (kcols kt+0..31, kt+32..63), chained over d=64
    f32x16 sc0, sc1;
    #pragma unroll
    for (int s = 0; s < 4; s++){
      int cp = (2*s + H) ^ (l32 & 7);
      bf16x8 kf0 = *reinterpret_cast<bf16x8*>(&Ks[l32*64 + cp*8]);
      bf16x8 kf1 = *reinterpret_cast<bf16x8*>(&Ks[(32 + l32)*64 + cp*8]);
      if (s == 0){
        sc0 = __builtin_amdgcn_mfma_f32_32x32x16_bf16(kf0, qf[0], zero16(), 0, 0, 0);
        sc1 = __builtin_amdgcn_mfma_f32_32x32x16_bf16(kf1, qf[0], zero16(), 0, 0, 0);
      } else {
        sc0 = __builtin_amdgcn_mfma_f32_32x32x16_bf16(kf0, qf[s], sc0, 0, 0, 0);
        sc1 = __builtin_amdgcn_mfma_f32_32x32x16_bf16(kf1, qf[s], sc1, 0, 0, 0);
      }
    }
    // exp (scores already in log2 domain; mask folded into the argument)
    // C-layout: lane owns q-col=l32; kcol = kt + t*32 + 8g + 4H + r (reg=4g+r)
    pk8 grp[2][4];
    #pragma unroll
    for (int t = 0; t < 2; t++){
      const f32x16& s = t ? sc1 : sc0;
      #pragma unroll
      for (int g = 0; g < 4; g++){
        int kcol = kt + t*32 + 8*g + 4*H;
        float4 mv = *reinterpret_cast<const float4*>(&mask[(size_t)b*S + kcol]);
        float p0 = EXP2F(fmaf(mv.x, MBIAS_C, s[4*g+0]));
        float p1 = EXP2F(fmaf(mv.y, MBIAS_C, s[4*g+1]));
        float p2 = EXP2F(fmaf(mv.z, MBIAS_C, s[4*g+2]));
        float p3 = EXP2F(fmaf(mv.w, MBIAS_C, s[4*g+3]));
        lacc += (p0 + p1) + (p2 + p3);
        pk8 w;
        w.b4[0] = (bf16_t)p0; w.b4[1] = (bf16_t)p1; w.b4[2] = (bf16_t)p2; w.b4[3] = (bf16_t)p3;
        grp[t][g] = w;
      }
    }
    // PV with register transpose: window kk (k16), t=kk>>1, w=kk&1.
    // A-frag(lane H') = [grp(g=2w+H') from H=0 lane | same g from H=1 lane]
    #pragma unroll
    for (int kk = 0; kk < 4; kk++){
      int t = kk >> 1, w = kk & 1;
      uint2 ga = grp[t][2*w].u2;      // this lane's g=2w quad
      uint2 gb = grp[t][2*w+1].u2;    // this lane's g=2w+1 quad
      uint2 send = H ? ga : gb;
      uint2 recv;
      recv.x = (unsigned)__shfl_xor((int)send.x, 32);
      recv.y = (unsigned)__shfl_xor((int)send.y, 32);
      pk16 fr;
      fr.h[0] = H ? recv : ga;
      fr.h[1] = H ? gb : recv;
      int cp = (2*kk + H) ^ (l32 & 7);
      bf16x8 vf0 = *reinterpret_cast<bf16x8*>(&Vts[l32*64 + cp*8]);
      bf16x8 vf1 = *reinterpret_cast<bf16x8*>(&Vts[(32 + l32)*64 + cp*8]);
      o0 = __builtin_amdgcn_mfma_f32_32x32x16_bf16(fr.b8, vf0, o0, 0, 0, 0);
      o1 = __builtin_amdgcn_mfma_f32_32x32x16_bf16(fr.b8, vf1, o1, 0, 0, 0);
    }
  }
  // l: lane's partial covers its kcol subset; combine across H halves
  float lfull = lacc + __shfl_xor(lacc, 32);
  Lbuf[wave*32 + l32] = lfull;   // both H write same value (benign); same-wave read below
  // epilogue: PV C-layout: lane col = d = l32 (+32 for o1), rows q = 8g+4H+r
  #pragma unroll
  for (int g = 0; g < 4; g++){
    f32x4 lv = *reinterpret_cast<f32x4*>(&Lbuf[wave*32 + 8*g + 4*H]);
    #pragma unroll
    for (int r = 0; r < 4; r++){
      float inv = 1.f / lv[r];
      int grow = qt*128 + wave*32 + 8*g + 4*H + r;
      size_t base = (size_t)(b*S + grow) * D + h*HD;
      ctx[base + l32]      = (bf16_t)(o0[4*g + r] * inv);
      ctx[base + 32 + l32] = (bf16_t)(o1[4*g + r] * inv);
    }
  }
}

extern "C" void kernel_launch(void* const* d_in, const int* in_sizes, int n_in,
                              void* d_out, int out_size, void* d_ws, size_t ws_size,
                              hipStream_t stream){
  const float* q    = (const float*)d_in[0];
  const float* k    = (const float*)d_in[1];
  const float* v    = (const float*)d_in[2];
  const float* mask = (const float*)d_in[3];
  const float* Wq   = (const float*)d_in[4];
  const float* bq   = (const float*)d_in[5];
  const float* Wk   = (const float*)d_in[6];
  const float* bk   = (const float*)d_in[7];
  const float* Wv   = (const float*)d_in[8];
  const float* bv   = (const float*)d_in[9];
  const float* Wo   = (const float*)d_in[10];
  const float* bo   = (const float*)d_in[11];

  char* ws = (char*)d_ws;
  bf16_t* qp    = (bf16_t*)(ws);               // [0, 8 MiB)
  bf16_t* kp    = (bf16_t*)(ws + 8388608);     // [8, 16)
  bf16_t* vh    = (bf16_t*)(ws + 16777216);    // [16, 24)
  bf16_t* Wcat  = (bf16_t*)(ws + 25165824);    // [24, 30)
  bf16_t* Wot   = (bf16_t*)(ws + 31457280);    // [30, 32)
  bf16_t* Vt    = (bf16_t*)(ws + 33554432);    // [32, 40)
  bf16_t* ctx   = (bf16_t*)(ws + 41943040);    // [40, 48)
  bf16_t* qkvin = (bf16_t*)(ws + 33554432);    // [32, 56) path A only; dead before Vt/ctx live

  wtrans4_kernel<<<dim3(32,32,4), dim3(32,8), 0, stream>>>(Wq, Wk, Wv, Wo, Wcat, Wot);
  if (ws_size >= 58720256){
    cast3_kernel<<<dim3(4096,3), 256, 0, stream>>>(q, k, v, qkvin);
    gemm_qkv_bf<<<dim3(24,32), 256, 0, stream>>>(qkvin, Wcat, bq, bk, bv, qp, kp, vh);
  } else {
    gemm_qkv_f32<<<dim3(24,32), 256, 0, stream>>>(q, k, v, Wcat, bq, bk, bv, qp, kp, vh);
  }
  vtrans_kernel<<<dim3(32,16,2), 256, 0, stream>>>(vh, Vt);
  attn_kernel<<<dim3(16,16,2), 256, 0, stream>>>(qp, kp, Vt, mask, ctx);
  gemm_out<<<dim3(16,32), 256, 0, stream>>>(ctx, Wot, bo, (float*)d_out);
}

// Round 7
// 241.666 us; speedup vs baseline: 1.1118x; 1.0916x over previous
//
#include <hip/hip_runtime.h>
#include <math.h>

typedef __bf16 bf16_t;
typedef __bf16 bf16x8 __attribute__((ext_vector_type(8)));
typedef __bf16 bf16x4v __attribute__((ext_vector_type(4)));
typedef float f32x4 __attribute__((ext_vector_type(4)));
typedef float f32x16 __attribute__((ext_vector_type(16)));

#define LOG2E 1.4426950408889634f
#define MBIAS_C (-1e12f * LOG2E)

#if __has_builtin(__builtin_amdgcn_exp2f)
#define EXP2F(x) __builtin_amdgcn_exp2f(x)
#else
#define EXP2F(x) exp2f(x)
#endif

typedef __attribute__((address_space(1))) const unsigned int g_u32;
typedef __attribute__((address_space(3))) unsigned int l_u32;
__device__ __forceinline__ void load_lds_16B(const void* g, void* l){
  __builtin_amdgcn_global_load_lds((g_u32*)g, (l_u32*)l, 16, 0, 0);
}

__device__ __forceinline__ f32x16 zero16(){
  f32x16 z;
  #pragma unroll
  for (int i = 0; i < 16; i++) z[i] = 0.f;
  return z;
}

typedef union { bf16x4v b4; uint2 u2; } pk8;
typedef union { uint2 h[2]; bf16x8 b8; } pk16;

// ---------------- cast q,k,v fp32 -> bf16 planes ----------------
__global__ __launch_bounds__(256) void cast3_kernel(const float* __restrict__ q,
                                                    const float* __restrict__ k,
                                                    const float* __restrict__ v,
                                                    bf16_t* __restrict__ out){
  int z = blockIdx.y;
  const float* x = (z == 0) ? q : (z == 1) ? k : v;
  int i = blockIdx.x * 256 + threadIdx.x;
  float4 f = reinterpret_cast<const float4*>(x)[i];
  bf16x4v w;
  w[0] = (bf16_t)f.x; w[1] = (bf16_t)f.y; w[2] = (bf16_t)f.z; w[3] = (bf16_t)f.w;
  reinterpret_cast<bf16x4v*>(out + (size_t)z * 4194304)[i] = w;
}

// ---------------- weight transpose+cast ----------------
__global__ __launch_bounds__(256) void wtrans4_kernel(const float* __restrict__ Wq,
                                                      const float* __restrict__ Wk,
                                                      const float* __restrict__ Wv,
                                                      const float* __restrict__ Wo,
                                                      bf16_t* __restrict__ Wcat,
                                                      bf16_t* __restrict__ Wot){
  __shared__ float T[32][33];
  int z = blockIdx.z;
  const float* W = (z == 0) ? Wq : (z == 1) ? Wk : (z == 2) ? Wv : Wo;
  bf16_t* dst = (z < 3) ? (Wcat + (size_t)z * 1024 * 1024) : Wot;
  int x = threadIdx.x, y = threadIdx.y;
  int k0 = blockIdx.y * 32, n0 = blockIdx.x * 32;
  #pragma unroll
  for (int i = 0; i < 4; i++) T[y + 8*i][x] = W[(size_t)(k0 + y + 8*i) * 1024 + n0 + x];
  __syncthreads();
  #pragma unroll
  for (int i = 0; i < 4; i++) dst[(size_t)(n0 + y + 8*i) * 1024 + k0 + x] = (bf16_t)T[x][y + 8*i];
}

// ---------------- shared epilogue for QKV GEMMs: write q/k/v planes ----------------
__device__ __forceinline__ void qkv_epilogue(f32x4 (&acc)[4][4], int seg, int n0g, int m0,
                                             int wm, int wn, int l16, int lq,
                                             const float* bias, bf16_t* qp, bf16_t* kp,
                                             bf16_t* vh){
  bf16_t* Cp = (seg == 0) ? qp : (seg == 1) ? kp : vh;
  float scale = (seg == 0) ? 0.125f * LOG2E : 1.0f;  // fold softmax scale + log2e into Q
  #pragma unroll
  for (int ti = 0; ti < 4; ti++){
    #pragma unroll
    for (int tj = 0; tj < 4; tj++){
      int col = (n0g + wn + tj*16 + l16) & 1023;
      float bvv = bias[col];
      #pragma unroll
      for (int r = 0; r < 4; r++){
        int row = m0 + wm + ti*16 + lq*4 + r;
        Cp[(size_t)row * 1024 + col] = (bf16_t)((acc[ti][tj][r] + bvv) * scale);
      }
    }
  }
}

// ---------------- fused QKV GEMM, all-bf16 (path A) ----------------
__global__ __launch_bounds__(256) void gemm_qkv_bf(const bf16_t* __restrict__ qkvin,
                                                   const bf16_t* __restrict__ Wcat,
                                                   const float* __restrict__ bq,
                                                   const float* __restrict__ bk,
                                                   const float* __restrict__ bv,
                                                   bf16_t* __restrict__ qp,
                                                   bf16_t* __restrict__ kp,
                                                   bf16_t* __restrict__ vh){
  const int K = 1024;
  __shared__ __align__(16) bf16_t As[128*32];
  __shared__ __align__(16) bf16_t Bs[128*32];
  int tid = threadIdx.x, wave = tid >> 6, lane = tid & 63;
  int l16 = lane & 15, lq = lane >> 4;
  int n0g = blockIdx.x * 128;
  int seg = n0g >> 10;
  const bf16_t* A   = qkvin + (size_t)seg * 4194304;
  const float* bias = (seg == 0) ? bq : (seg == 1) ? bk : bv;
  int m0 = blockIdx.y * 128;
  int wm = (wave >> 1) * 64, wn = (wave & 1) * 64;
  int cposR = lq ^ ((l16 >> 2) & 3);
  f32x4 acc[4][4] = {};
  for (int kt = 0; kt < K; kt += 32){
    __syncthreads();
    #pragma unroll
    for (int i = 0; i < 2; i++){
      int u = tid + 256*i;
      int r = u >> 2, cpos = u & 3, cg = cpos ^ ((r >> 2) & 3);
      int ldsoff = (wave*64 + 256*i) * 16;
      load_lds_16B(&A[(size_t)(m0 + r) * K + kt + cg*8], (char*)As + ldsoff);
      load_lds_16B(&Wcat[(size_t)(n0g + r) * K + kt + cg*8], (char*)Bs + ldsoff);
    }
    __syncthreads();
    bf16x8 af[4], bfr[4];
    #pragma unroll
    for (int t = 0; t < 4; t++) af[t]  = *reinterpret_cast<bf16x8*>(&As[(wm + t*16 + l16)*32 + cposR*8]);
    #pragma unroll
    for (int t = 0; t < 4; t++) bfr[t] = *reinterpret_cast<bf16x8*>(&Bs[(wn + t*16 + l16)*32 + cposR*8]);
    #pragma unroll
    for (int ti = 0; ti < 4; ti++)
      #pragma unroll
      for (int tj = 0; tj < 4; tj++)
        acc[ti][tj] = __builtin_amdgcn_mfma_f32_16x16x32_bf16(af[ti], bfr[tj], acc[ti][tj], 0, 0, 0);
  }
  qkv_epilogue(acc, seg, n0g, m0, wm, wn, l16, lq, bias, qp, kp, vh);
}

// ---------------- fused QKV GEMM, fp32-A fused-cvt (path B fallback) ----------------
__global__ __launch_bounds__(256) void gemm_qkv_f32(const float* __restrict__ qi,
                                                    const float* __restrict__ ki,
                                                    const float* __restrict__ vi,
                                                    const bf16_t* __restrict__ Wcat,
                                                    const float* __restrict__ bq,
                                                    const float* __restrict__ bk,
                                                    const float* __restrict__ bv,
                                                    bf16_t* __restrict__ qp,
                                                    bf16_t* __restrict__ kp,
                                                    bf16_t* __restrict__ vh){
  const int K = 1024;
  __shared__ __align__(16) float  Asf[128*32];
  __shared__ __align__(16) bf16_t Bs[128*32];
  int tid = threadIdx.x, wave = tid >> 6, lane = tid & 63;
  int l16 = lane & 15, lq = lane >> 4;
  int n0g = blockIdx.x * 128;
  int seg = n0g >> 10;
  const float* A    = (seg == 0) ? qi : (seg == 1) ? ki : vi;
  const float* bias = (seg == 0) ? bq : (seg == 1) ? bk : bv;
  int m0 = blockIdx.y * 128;
  int wm = (wave >> 1) * 64, wn = (wave & 1) * 64;
  int cposR = lq ^ ((l16 >> 2) & 3);
  int ca0 = (2*lq)     ^ (l16 & 7);
  int ca1 = (2*lq + 1) ^ (l16 & 7);
  f32x4 acc[4][4] = {};
  for (int kt = 0; kt < K; kt += 32){
    __syncthreads();
    #pragma unroll
    for (int i = 0; i < 4; i++){
      int u = tid + 256*i;
      int r = u >> 3, cpos = u & 7, cg = cpos ^ (r & 7);
      load_lds_16B(&A[(size_t)(m0 + r) * K + kt + cg*4], (char*)Asf + (wave*64 + 256*i)*16);
    }
    #pragma unroll
    for (int i = 0; i < 2; i++){
      int u = tid + 256*i;
      int r = u >> 2, cpos = u & 3, cg = cpos ^ ((r >> 2) & 3);
      load_lds_16B(&Wcat[(size_t)(n0g + r) * K + kt + cg*8], (char*)Bs + (wave*64 + 256*i)*16);
    }
    __syncthreads();
    bf16x8 af[4], bfr[4];
    #pragma unroll
    for (int t = 0; t < 4; t++){
      int row = wm + t*16 + l16;
      f32x4 x0 = *reinterpret_cast<f32x4*>(&Asf[row*32 + ca0*4]);
      f32x4 x1 = *reinterpret_cast<f32x4*>(&Asf[row*32 + ca1*4]);
      bf16x8 a;
      a[0] = (bf16_t)x0[0]; a[1] = (bf16_t)x0[1]; a[2] = (bf16_t)x0[2]; a[3] = (bf16_t)x0[3];
      a[4] = (bf16_t)x1[0]; a[5] = (bf16_t)x1[1]; a[6] = (bf16_t)x1[2]; a[7] = (bf16_t)x1[3];
      af[t] = a;
    }
    #pragma unroll
    for (int t = 0; t < 4; t++) bfr[t] = *reinterpret_cast<bf16x8*>(&Bs[(wn + t*16 + l16)*32 + cposR*8]);
    #pragma unroll
    for (int ti = 0; ti < 4; ti++)
      #pragma unroll
      for (int tj = 0; tj < 4; tj++)
        acc[ti][tj] = __builtin_amdgcn_mfma_f32_16x16x32_bf16(af[ti], bfr[tj], acc[ti][tj], 0, 0, 0);
  }
  qkv_epilogue(acc, seg, n0g, m0, wm, wn, l16, lq, bias, qp, kp, vh);
}

// ---------------- output GEMM: d_out = ctx @ Wot^T + bo, fp32 out ----------------
__global__ __launch_bounds__(256) void gemm_out(const bf16_t* __restrict__ A,
                                                const bf16_t* __restrict__ Bt,
                                                const float* __restrict__ bias,
                                                float* __restrict__ C){
  const int K = 1024, N = 1024;
  __shared__ __align__(16) bf16_t As[128*64];
  __shared__ __align__(16) bf16_t Bs[64*64];
  int tid = threadIdx.x, wave = tid >> 6, lane = tid & 63;
  int l16 = lane & 15, lq = lane >> 4;
  int m0 = blockIdx.y * 128, n0 = blockIdx.x * 64;
  int wm = wave * 32;
  f32x4 acc[2][4] = {};
  for (int kt = 0; kt < K; kt += 64){
    __syncthreads();
    #pragma unroll
    for (int i = 0; i < 4; i++){
      int u = tid + 256*i;
      int r = u >> 3, cpos = u & 7, cg = cpos ^ (r & 7);
      load_lds_16B(&A[(size_t)(m0 + r) * K + kt + cg*8], (char*)As + (wave*64 + 256*i)*16);
    }
    #pragma unroll
    for (int i = 0; i < 2; i++){
      int u = tid + 256*i;
      int r = u >> 3, cpos = u & 7, cg = cpos ^ (r & 7);
      load_lds_16B(&Bt[(size_t)(n0 + r) * K + kt + cg*8], (char*)Bs + (wave*64 + 256*i)*16);
    }
    __syncthreads();
    #pragma unroll
    for (int kk = 0; kk < 2; kk++){
      bf16x8 af[2], bfr[4];
      #pragma unroll
      for (int t = 0; t < 2; t++){
        int row = wm + t*16 + l16, cpos = (kk*4 + lq) ^ (l16 & 7);
        af[t] = *reinterpret_cast<bf16x8*>(&As[row*64 + cpos*8]);
      }
      #pragma unroll
      for (int t = 0; t < 4; t++){
        int row = t*16 + l16, cpos = (kk*4 + lq) ^ (l16 & 7);
        bfr[t] = *reinterpret_cast<bf16x8*>(&Bs[row*64 + cpos*8]);
      }
      #pragma unroll
      for (int ti = 0; ti < 2; ti++)
        #pragma unroll
        for (int tj = 0; tj < 4; tj++)
          acc[ti][tj] = __builtin_amdgcn_mfma_f32_16x16x32_bf16(af[ti], bfr[tj], acc[ti][tj], 0, 0, 0);
    }
  }
  #pragma unroll
  for (int ti = 0; ti < 2; ti++){
    #pragma unroll
    for (int tj = 0; tj < 4; tj++){
      int col = n0 + tj*16 + l16;
      float bvv = bias[col];
      #pragma unroll
      for (int r = 0; r < 4; r++){
        int row = m0 + wm + ti*16 + lq*4 + r;
        C[(size_t)row * N + col] = acc[ti][tj][r] + bvv;
      }
    }
  }
}

// ---------------- per-head V transpose: vh[b*2048+s][h*64+d] -> Vt[(b*16+h)*64+d][s] ----------------
__global__ __launch_bounds__(256) void vtrans_kernel(const bf16_t* __restrict__ vh,
                                                     bf16_t* __restrict__ Vt){
  __shared__ bf16_t T[64][72];
  int tid = threadIdx.x;
  int s0 = blockIdx.x * 64, h = blockIdx.y, b = blockIdx.z;
  #pragma unroll
  for (int i = 0; i < 2; i++){
    int u = tid + 256*i;
    int r = u >> 3, c = (u & 7) * 8;
    *reinterpret_cast<uint4*>(&T[r][c]) =
      *reinterpret_cast<const uint4*>(&vh[(size_t)(b*2048 + s0 + r) * 1024 + h*64 + c]);
  }
  __syncthreads();
  #pragma unroll
  for (int i = 0; i < 2; i++){
    int u = tid + 256*i;
    int d = u >> 3, cs = (u & 7) * 8;
    bf16_t t8[8];
    #pragma unroll
    for (int j = 0; j < 8; j++) t8[j] = T[cs + j][d];
    *reinterpret_cast<uint4*>(&Vt[(size_t)((b*16 + h)*64 + d) * 2048 + s0 + cs]) =
      *reinterpret_cast<uint4*>(t8);
  }
}

// ---------------- flash attention v4: 32x32x16 MFMA, register P-transpose, q x k wave split ----------------
// Block: 64 q-rows, 4 waves = (qhalf, khalf). Each wave: 32 q x 32 keys per 64-key tile.
// Sc^T = mfma(K,Q) -> lane owns q-col l32; exp in regs; C->A transpose via 2 shfl_xor(32)
// per 16-key window; PV partial O per k-half, combined via LDS epilogue. Mask row staged
// to LDS once per block (per-tile reads are quarter-wave broadcasts = free).
// LDS 24.6 KB, grid 1024 -> 4 blocks/CU (~16 waves/CU).
__global__ __launch_bounds__(256) void attn_kernel(const bf16_t* __restrict__ qp,
                                                   const bf16_t* __restrict__ kp,
                                                   const bf16_t* __restrict__ vt,
                                                   const float* __restrict__ mask,
                                                   bf16_t* __restrict__ ctx){
  const int S = 2048, D = 1024, HD = 64;
  __shared__ __align__(16) char smem[25216];
  bf16_t* Ks   = (bf16_t*)smem;             // [64][64] 8 KB
  bf16_t* Vts  = (bf16_t*)(smem + 8192);    // [64][64] 8 KB ([d][s])
  float*  Mb   = (float*)(smem + 16384);    // [2048] mask row, 8 KB
  float*  Lsum = (float*)(smem + 24576);    // [64]
  float*  Lcomb= (float*)(smem + 24832);    // [64]
  float*  Opart= (float*)smem;              // epilogue: [2 qhalf][32 regs][64 lanes] = 16 KB (unions Ks+Vts)
  int tid = threadIdx.x, wave = tid >> 6, lane = tid & 63;
  int l32 = lane & 31, H = lane >> 5;
  int qhalf = wave & 1, khalf = wave >> 1;
  int qt = blockIdx.x, h = blockIdx.y, b = blockIdx.z;
  const bf16_t* Qg = qp + (size_t)b*S*D + h*HD;
  const bf16_t* Kg = kp + (size_t)b*S*D + h*HD;
  const bf16_t* Vg = vt + (size_t)(b*16 + h)*HD*S;
  const float*  Mg = mask + (size_t)b*S;

  // stage mask row (2048 floats) once
  #pragma unroll
  for (int i = 0; i < 2; i++)
    load_lds_16B(&Mg[(tid + 256*i)*4], (char*)Mb + (wave*64 + 256*i)*16);

  // Q fragments straight from global: B-operand, lane n=qrow, k=d=16s+8H+j
  int qrow = qt*64 + qhalf*32 + l32;
  bf16x8 qf[4];
  #pragma unroll
  for (int s = 0; s < 4; s++)
    qf[s] = *reinterpret_cast<const bf16x8*>(&Qg[(size_t)qrow * D + s*16 + 8*H]);

  f32x16 o0 = zero16(), o1 = zero16();
  float lacc = 0.f;
  int krow = khalf*32 + l32;

  for (int kt = 0; kt < S; kt += 64){
    __syncthreads();
    #pragma unroll
    for (int i = 0; i < 2; i++){
      int u = tid + 256*i;
      int r = u >> 3, c = u & 7, cg = c ^ (r & 7);
      load_lds_16B(&Kg[(size_t)(kt + r) * D + cg*8], (char*)Ks + (wave*64 + 256*i)*16);
    }
    #pragma unroll
    for (int i = 0; i < 2; i++){
      int u = tid + 256*i;
      int r = u >> 3, c = u & 7, cg = c ^ (r & 7);
      load_lds_16B(&Vg[(size_t)r * S + kt + cg*8], (char*)Vts + (wave*64 + 256*i)*16);
    }
    __syncthreads();

    // QK: one 32x32 Sc^T tile (this wave's 32 keys x its 32 q), chained over d=64
    f32x16 sc;
    #pragma unroll
    for (int s = 0; s < 4; s++){
      int cp = (2*s + H) ^ (l32 & 7);  // krow&7 == l32&7
      bf16x8 kf = *reinterpret_cast<bf16x8*>(&Ks[krow*64 + cp*8]);
      if (s == 0) sc = __builtin_amdgcn_mfma_f32_32x32x16_bf16(kf, qf[0], zero16(), 0, 0, 0);
      else        sc = __builtin_amdgcn_mfma_f32_32x32x16_bf16(kf, qf[s], sc, 0, 0, 0);
    }
    // exp; C-layout: lane owns q-col l32; tile-key = khalf*32 + 8g + 4H + r (reg=4g+r)
    pk8 grp[4];
    #pragma unroll
    for (int g = 0; g < 4; g++){
      float4 mv = *reinterpret_cast<float4*>(&Mb[kt + khalf*32 + 8*g + 4*H]);  // broadcast
      float p0 = EXP2F(fmaf(mv.x, MBIAS_C, sc[4*g+0]));
      float p1 = EXP2F(fmaf(mv.y, MBIAS_C, sc[4*g+1]));
      float p2 = EXP2F(fmaf(mv.z, MBIAS_C, sc[4*g+2]));
      float p3 = EXP2F(fmaf(mv.w, MBIAS_C, sc[4*g+3]));
      lacc += (p0 + p1) + (p2 + p3);
      pk8 w;
      w.b4[0] = (bf16_t)p0; w.b4[1] = (bf16_t)p1; w.b4[2] = (bf16_t)p2; w.b4[3] = (bf16_t)p3;
      grp[g] = w;
    }
    // PV with register transpose; window kk covers tile-keys khalf*32 + 16kk + 8H + j
    #pragma unroll
    for (int kk = 0; kk < 2; kk++){
      uint2 ga = grp[2*kk].u2;
      uint2 gb = grp[2*kk+1].u2;
      uint2 send = H ? ga : gb;
      uint2 recv;
      recv.x = (unsigned)__shfl_xor((int)send.x, 32);
      recv.y = (unsigned)__shfl_xor((int)send.y, 32);
      pk16 fr;
      fr.h[0] = H ? recv : ga;
      fr.h[1] = H ? gb : recv;
      int cp = (4*khalf + 2*kk + H) ^ (l32 & 7);
      bf16x8 vf0 = *reinterpret_cast<bf16x8*>(&Vts[l32*64 + cp*8]);
      bf16x8 vf1 = *reinterpret_cast<bf16x8*>(&Vts[(32 + l32)*64 + cp*8]);
      o0 = __builtin_amdgcn_mfma_f32_32x32x16_bf16(fr.b8, vf0, o0, 0, 0, 0);
      o1 = __builtin_amdgcn_mfma_f32_32x32x16_bf16(fr.b8, vf1, o1, 0, 0, 0);
    }
  }
  // epilogue: combine k-halves through LDS (overlays Ks/Vts), normalize, store
  float lfull = lacc + __shfl_xor(lacc, 32);
  __syncthreads();
  if (khalf == 1){
    #pragma unroll
    for (int reg = 0; reg < 16; reg++){
      Opart[qhalf*2048 + reg*64 + lane]        = o0[reg];
      Opart[qhalf*2048 + 1024 + reg*64 + lane] = o1[reg];
    }
    if (H == 0) Lsum[qhalf*32 + l32] = lfull;
  }
  __syncthreads();
  if (khalf == 0){
    #pragma unroll
    for (int reg = 0; reg < 16; reg++){
      o0[reg] += Opart[qhalf*2048 + reg*64 + lane];
      o1[reg] += Opart[qhalf*2048 + 1024 + reg*64 + lane];
    }
    lfull += Lsum[qhalf*32 + l32];
    Lcomb[qhalf*32 + l32] = lfull;  // same-wave DS ordering; no barrier needed
    #pragma unroll
    for (int g = 0; g < 4; g++){
      f32x4 lv = *reinterpret_cast<f32x4*>(&Lcomb[qhalf*32 + 8*g + 4*H]);
      #pragma unroll
      for (int r = 0; r < 4; r++){
        float inv = 1.f / lv[r];
        int grow = qt*64 + qhalf*32 + 8*g + 4*H + r;
        size_t base = (size_t)(b*S + grow) * D + h*HD;
        ctx[base + l32]      = (bf16_t)(o0[4*g + r] * inv);
        ctx[base + 32 + l32] = (bf16_t)(o1[4*g + r] * inv);
      }
    }
  }
}

extern "C" void kernel_launch(void* const* d_in, const int* in_sizes, int n_in,
                              void* d_out, int out_size, void* d_ws, size_t ws_size,
                              hipStream_t stream){
  const float* q    = (const float*)d_in[0];
  const float* k    = (const float*)d_in[1];
  const float* v    = (const float*)d_in[2];
  const float* mask = (const float*)d_in[3];
  const float* Wq   = (const float*)d_in[4];
  const float* bq   = (const float*)d_in[5];
  const float* Wk   = (const float*)d_in[6];
  const float* bk   = (const float*)d_in[7];
  const float* Wv   = (const float*)d_in[8];
  const float* bv   = (const float*)d_in[9];
  const float* Wo   = (const float*)d_in[10];
  const float* bo   = (const float*)d_in[11];

  char* ws = (char*)d_ws;
  bf16_t* qp    = (bf16_t*)(ws);               // [0, 8 MiB)
  bf16_t* kp    = (bf16_t*)(ws + 8388608);     // [8, 16)
  bf16_t* vh    = (bf16_t*)(ws + 16777216);    // [16, 24)
  bf16_t* Wcat  = (bf16_t*)(ws + 25165824);    // [24, 30)
  bf16_t* Wot   = (bf16_t*)(ws + 31457280);    // [30, 32)
  bf16_t* Vt    = (bf16_t*)(ws + 33554432);    // [32, 40)
  bf16_t* ctx   = (bf16_t*)(ws + 41943040);    // [40, 48)
  bf16_t* qkvin = (bf16_t*)(ws + 33554432);    // [32, 56) path A only; dead before Vt/ctx live

  wtrans4_kernel<<<dim3(32,32,4), dim3(32,8), 0, stream>>>(Wq, Wk, Wv, Wo, Wcat, Wot);
  if (ws_size >= 58720256){
    cast3_kernel<<<dim3(4096,3), 256, 0, stream>>>(q, k, v, qkvin);
    gemm_qkv_bf<<<dim3(24,32), 256, 0, stream>>>(qkvin, Wcat, bq, bk, bv, qp, kp, vh);
  } else {
    gemm_qkv_f32<<<dim3(24,32), 256, 0, stream>>>(q, k, v, Wcat, bq, bk, bv, qp, kp, vh);
  }
  vtrans_kernel<<<dim3(32,16,2), 256, 0, stream>>>(vh, Vt);
  attn_kernel<<<dim3(32,16,2), 256, 0, stream>>>(qp, kp, Vt, mask, ctx);
  gemm_out<<<dim3(16,32), 256, 0, stream>>>(ctx, Wot, bo, (float*)d_out);
}